// Round 1
// baseline (958.566 us; speedup 1.0000x reference)
//
#include <hip/hip_runtime.h>

// Problem constants
#define NC   8192
#define NEFF 8192
#define DIN  256
#define DOUT 128
#define SCALE 0.08838834764831843f  // 1/sqrt(128)

typedef float  f32x4  __attribute__((ext_vector_type(4)));
typedef short  s16x8  __attribute__((ext_vector_type(8)));

// RNE float -> bf16 (as short)
__device__ __forceinline__ short f2bf(float f) {
    unsigned int u = __builtin_bit_cast(unsigned int, f);
    u += 0x7FFFu + ((u >> 16) & 1u);
    return (short)(u >> 16);
}

__device__ __forceinline__ s16x8 ld8(const short* p) {
    return *(const s16x8*)__builtin_assume_aligned(p, 16);
}

// ---------------------------------------------------------------------------
// Kernel 1: QKV projections.  grid(128, 3): blockIdx.x = 64-row block,
// blockIdx.y = matrix (0=Q scaled, 1=K, 2=V transposed).
// ---------------------------------------------------------------------------
__global__ __launch_bounds__(256, 2) void qkv_kernel(
    const float* __restrict__ embc, const float* __restrict__ embe,
    const float* __restrict__ Wq, const float* __restrict__ bq,
    const float* __restrict__ Wk, const float* __restrict__ bk,
    const float* __restrict__ Wv, const float* __restrict__ bv,
    short* __restrict__ Qs, short* __restrict__ Kb, short* __restrict__ Vt)
{
    const int mat = blockIdx.y;
    const float* src  = (mat == 0) ? embc : embe;
    const float* W    = (mat == 0) ? Wq : (mat == 1 ? Wk : Wv);
    const float* bias = (mat == 0) ? bq : (mat == 1 ? bk : bv);

    // W^T staged in bf16, half of K at a time. stride 136 shorts = 272 B
    // (multiple of 16 B for ds_read_b128; 68 dwords -> +4 bank shift/row).
    __shared__ short wt[DOUT][136];
    __shared__ short vbuf[DOUT][72];   // V transpose staging (mat==2 only)

    const int tid  = threadIdx.x;
    const int wave = tid >> 6, lane = tid & 63;
    const int quad = lane >> 4, ln16 = lane & 15;
    const int rowbase = blockIdx.x * 64;
    const int arow = rowbase + wave * 16 + ln16;   // A-fragment row

    f32x4 acc[8];
#pragma unroll
    for (int i = 0; i < 8; i++) acc[i] = (f32x4){0.f, 0.f, 0.f, 0.f};

    for (int h = 0; h < 2; h++) {
        __syncthreads();   // WAR vs previous half's reads
        {   // stage W[h*128 .. +127][0..127] transposed into wt (bf16)
            const int n0 = (tid & 31) * 4;
            const int kb = tid >> 5;               // 0..7
#pragma unroll
            for (int i = 0; i < 16; i++) {
                const int k = kb + i * 8;          // 0..127 (local)
                const float4 w4 = *(const float4*)(W + (size_t)(h * 128 + k) * DOUT + n0);
                wt[n0 + 0][k] = f2bf(w4.x);
                wt[n0 + 1][k] = f2bf(w4.y);
                wt[n0 + 2][k] = f2bf(w4.z);
                wt[n0 + 3][k] = f2bf(w4.w);
            }
        }
        __syncthreads();

        // A-fragments for this K-half (f32 -> bf16 in regs)
        s16x8 afr[4];
#pragma unroll
        for (int kc = 0; kc < 4; kc++) {
            const float* ap = src + (size_t)arow * DIN + h * 128 + kc * 32 + quad * 8;
            const float4 a0 = *(const float4*)ap;
            const float4 a1 = *(const float4*)(ap + 4);
            s16x8 a;
            a[0] = f2bf(a0.x); a[1] = f2bf(a0.y); a[2] = f2bf(a0.z); a[3] = f2bf(a0.w);
            a[4] = f2bf(a1.x); a[5] = f2bf(a1.y); a[6] = f2bf(a1.z); a[7] = f2bf(a1.w);
            afr[kc] = a;
        }
#pragma unroll
        for (int nt = 0; nt < 8; nt++) {
#pragma unroll
            for (int kc = 0; kc < 4; kc++) {
                const s16x8 b = ld8(&wt[nt * 16 + ln16][kc * 32 + quad * 8]);
                acc[nt] = __builtin_amdgcn_mfma_f32_16x16x32_bf16(afr[kc], b, acc[nt], 0, 0, 0);
            }
        }
    }

    if (mat < 2) {
        short* dst = (mat == 0) ? Qs : Kb;
        const float sc = (mat == 0) ? SCALE : 1.0f;
#pragma unroll
        for (int nt = 0; nt < 8; nt++) {
            const int col = nt * 16 + ln16;
            const float bb = bias[col];
#pragma unroll
            for (int r = 0; r < 4; r++) {
                const int row = rowbase + wave * 16 + quad * 4 + r;
                dst[(size_t)row * DOUT + col] = f2bf((acc[nt][r] + bb) * sc);
            }
        }
    } else {
        __syncthreads();
#pragma unroll
        for (int nt = 0; nt < 8; nt++) {
            const int col = nt * 16 + ln16;
            const float bb = bias[col];
#pragma unroll
            for (int r = 0; r < 4; r++) {
                const int row = wave * 16 + quad * 4 + r;   // within 64-row block
                vbuf[col][row] = f2bf(acc[nt][r] + bb);
            }
        }
        __syncthreads();
        // coalesced write of Vt[col][rowbase .. rowbase+64)
        const int col = tid >> 1, half = tid & 1;
        short* gp = Vt + (size_t)col * NC + rowbase + half * 32;
        const short* lp = &vbuf[col][half * 32];
#pragma unroll
        for (int i = 0; i < 4; i++)
            *(s16x8*)(gp + i * 8) = ld8(lp + i * 8);
    }
}

// ---------------------------------------------------------------------------
// Kernel 2: per-row sum of exp(masked scores) + bitmask pack.
// grid(256, 4): blockIdx.x = 32-row block, blockIdx.y = 2048-col strip.
// Wave w: rows 16*(w&1), cols 64*(w>>1) within each 128-col tile.
// ---------------------------------------------------------------------------
__global__ __launch_bounds__(256, 4) void stats_kernel(
    const int* __restrict__ mask, const short* __restrict__ Qs,
    const short* __restrict__ Kb, float* __restrict__ lsum,
    unsigned short* __restrict__ bm)
{
    const int rb = blockIdx.x, strip = blockIdx.y;
    const int tid  = threadIdx.x;
    const int wave = tid >> 6, lane = tid & 63;
    const int quad = lane >> 4, ln16 = lane & 15;
    const int rowbase = rb * 32 + (wave & 1) * 16;
    const int wcol = (wave >> 1) * 64;

    s16x8 aq[4];
#pragma unroll
    for (int kc = 0; kc < 4; kc++)
        aq[kc] = ld8(Qs + (size_t)(rowbase + ln16) * DOUT + kc * 32 + quad * 8);

    float lp[4] = {0.f, 0.f, 0.f, 0.f};

    for (int ct = 0; ct < 16; ct++) {
        const int colbase = strip * 2048 + ct * 128 + wcol;
        f32x4 c[4];
#pragma unroll
        for (int nt = 0; nt < 4; nt++) c[nt] = (f32x4){0.f, 0.f, 0.f, 0.f};
#pragma unroll
        for (int nt = 0; nt < 4; nt++)
#pragma unroll
            for (int kc = 0; kc < 4; kc++) {
                const s16x8 b = ld8(Kb + (size_t)(colbase + nt * 16 + ln16) * DOUT + kc * 32 + quad * 8);
                c[nt] = __builtin_amdgcn_mfma_f32_16x16x32_bf16(aq[kc], b, c[nt], 0, 0, 0);
            }

        unsigned int bits = 0;
#pragma unroll
        for (int r = 0; r < 4; r++) {
            const int row = rowbase + quad * 4 + r;
            const int* mrow = mask + (size_t)row * NEFF + colbase + ln16;
#pragma unroll
            for (int nt = 0; nt < 4; nt++) {
                if (mrow[nt * 16] != 0) {
                    lp[r] += __expf(c[nt][r]);
                    bits |= 1u << (r * 4 + nt);
                }
            }
        }
        const int gct = strip * 16 + ct;
        bm[((size_t)(rb * 64 + gct)) * 256 + tid] = (unsigned short)bits;
    }

#pragma unroll
    for (int r = 0; r < 4; r++) {
        float v = lp[r];
        v += __shfl_xor(v, 1); v += __shfl_xor(v, 2);
        v += __shfl_xor(v, 4); v += __shfl_xor(v, 8);
        if (ln16 == 0) atomicAdd(&lsum[rowbase + quad * 4 + r], v);
    }
}

// ---------------------------------------------------------------------------
// Kernel 3: recompute S, write normalized weights, fused O = W @ V.
// Same grid/wave structure as stats_kernel (bitmask indices must match).
// ---------------------------------------------------------------------------
__global__ __launch_bounds__(256, 3) void attn_kernel(
    const short* __restrict__ Qs, const short* __restrict__ Kb,
    const short* __restrict__ Vt, const float* __restrict__ lsum,
    const unsigned short* __restrict__ bm,
    float* __restrict__ outO, float* __restrict__ outW)
{
    __shared__ short wlds[4][16][72];   // per-wave W tile (16 rows x 64 cols), 144 B stride
    __shared__ float obuf[32][132];     // O merge buffer

    const int rb = blockIdx.x, strip = blockIdx.y;
    const int tid  = threadIdx.x;
    const int wave = tid >> 6, lane = tid & 63;
    const int quad = lane >> 4, ln16 = lane & 15;
    const int rowbase = rb * 32 + (wave & 1) * 16;
    const int wcol = (wave >> 1) * 64;

    s16x8 aq[4];
#pragma unroll
    for (int kc = 0; kc < 4; kc++)
        aq[kc] = ld8(Qs + (size_t)(rowbase + ln16) * DOUT + kc * 32 + quad * 8);

    float rl[4];
#pragma unroll
    for (int r = 0; r < 4; r++)
        rl[r] = 1.0f / lsum[rowbase + quad * 4 + r];

    f32x4 o[8];
#pragma unroll
    for (int i = 0; i < 8; i++) o[i] = (f32x4){0.f, 0.f, 0.f, 0.f};

    for (int ct = 0; ct < 16; ct++) {
        const int colbase = strip * 2048 + ct * 128 + wcol;
        f32x4 c[4];
#pragma unroll
        for (int nt = 0; nt < 4; nt++) c[nt] = (f32x4){0.f, 0.f, 0.f, 0.f};
#pragma unroll
        for (int nt = 0; nt < 4; nt++)
#pragma unroll
            for (int kc = 0; kc < 4; kc++) {
                const s16x8 b = ld8(Kb + (size_t)(colbase + nt * 16 + ln16) * DOUT + kc * 32 + quad * 8);
                c[nt] = __builtin_amdgcn_mfma_f32_16x16x32_bf16(aq[kc], b, c[nt], 0, 0, 0);
            }

        const int gct = strip * 16 + ct;
        const unsigned int bits = bm[((size_t)(rb * 64 + gct)) * 256 + tid];

#pragma unroll
        for (int r = 0; r < 4; r++) {
            const int row = rowbase + quad * 4 + r;
            float* wrow = outW + (size_t)row * NEFF + colbase + ln16;
#pragma unroll
            for (int nt = 0; nt < 4; nt++) {
                const float w = ((bits >> (r * 4 + nt)) & 1u) ? __expf(c[nt][r]) * rl[r] : 0.0f;
                wrow[nt * 16] = w;
                wlds[wave][quad * 4 + r][nt * 16 + ln16] = f2bf(w);
            }
        }
        __syncthreads();
        // A-fragments of W (C-layout -> A-layout via LDS), then PV MFMAs
        const s16x8 aw0 = ld8(&wlds[wave][ln16][quad * 8]);
        const s16x8 aw1 = ld8(&wlds[wave][ln16][32 + quad * 8]);
#pragma unroll
        for (int nt2 = 0; nt2 < 8; nt2++) {
            const short* vrow = Vt + (size_t)(nt2 * 16 + ln16) * NC + colbase;
            const s16x8 b0 = ld8(vrow + quad * 8);
            const s16x8 b1 = ld8(vrow + 32 + quad * 8);
            o[nt2] = __builtin_amdgcn_mfma_f32_16x16x32_bf16(aw0, b0, o[nt2], 0, 0, 0);
            o[nt2] = __builtin_amdgcn_mfma_f32_16x16x32_bf16(aw1, b1, o[nt2], 0, 0, 0);
        }
        __syncthreads();   // protect wlds WAR for next iteration
    }

    // merge partial O across wave pairs (0,2) and (1,3) via LDS
    if (wave < 2) {
#pragma unroll
        for (int nt2 = 0; nt2 < 8; nt2++)
#pragma unroll
            for (int r = 0; r < 4; r++)
                obuf[(wave & 1) * 16 + quad * 4 + r][nt2 * 16 + ln16] = o[nt2][r];
    }
    __syncthreads();
    if (wave >= 2) {
#pragma unroll
        for (int nt2 = 0; nt2 < 8; nt2++)
#pragma unroll
            for (int r = 0; r < 4; r++)
                obuf[(wave & 1) * 16 + quad * 4 + r][nt2 * 16 + ln16] += o[nt2][r];
    }
    __syncthreads();
    // strip-partial O -> global via f32 atomics (outO pre-zeroed)
#pragma unroll
    for (int i = 0; i < 16; i++) {
        const int idx = tid + i * 256;          // 0..4095
        const int row = idx >> 7, colf = idx & 127;
        atomicAdd(&outO[(size_t)(rb * 32 + row) * DOUT + colf], obuf[row][colf]);
    }
}

// ---------------------------------------------------------------------------
extern "C" void kernel_launch(void* const* d_in, const int* in_sizes, int n_in,
                              void* d_out, int out_size, void* d_ws, size_t ws_size,
                              hipStream_t stream) {
    (void)in_sizes; (void)n_in; (void)out_size; (void)ws_size;

    const float* embc = (const float*)d_in[0];
    const float* embe = (const float*)d_in[1];
    const int*   mask = (const int*)d_in[2];
    const float* Wq = (const float*)d_in[3];
    const float* bq = (const float*)d_in[4];
    const float* Wk = (const float*)d_in[5];
    const float* bk = (const float*)d_in[6];
    const float* Wv = (const float*)d_in[7];
    const float* bv = (const float*)d_in[8];

    char* ws = (char*)d_ws;
    short* Qs = (short*)(ws);                        // 2 MB  (bf16, pre-scaled)
    short* Kb = (short*)(ws + (2u << 20));           // 2 MB
    short* Vt = (short*)(ws + (4u << 20));           // 2 MB  (transposed [feat][col])
    float* lsum = (float*)(ws + (6u << 20));         // 32 KB
    unsigned short* bm = (unsigned short*)(ws + (8u << 20)); // 8 MB bitmask

    float* outO = (float*)d_out;                     // [8192,128]
    float* outW = outO + (size_t)NC * DOUT;          // [8192,8192]

    hipMemsetAsync(lsum, 0, NC * sizeof(float), stream);
    hipMemsetAsync(outO, 0, (size_t)NC * DOUT * sizeof(float), stream);

    qkv_kernel<<<dim3(128, 3), 256, 0, stream>>>(embc, embe, Wq, bq, Wk, bk, Wv, bv,
                                                 Qs, Kb, Vt);
    stats_kernel<<<dim3(256, 4), 256, 0, stream>>>(mask, Qs, Kb, lsum, bm);
    attn_kernel<<<dim3(256, 4), 256, 0, stream>>>(Qs, Kb, Vt, lsum, bm, outO, outW);
}